// Round 17
// baseline (332.757 us; speedup 1.0000x reference)
//
#include <hip/hip_runtime.h>
#include <hip/hip_bf16.h>
#include <stdint.h>
#include <math.h>

typedef __bf16 bf16;
typedef __bf16 bf16x8 __attribute__((ext_vector_type(8)));
typedef __bf16 bf16x4 __attribute__((ext_vector_type(4)));
typedef float  f32x4  __attribute__((ext_vector_type(4)));
typedef int    i32x4  __attribute__((ext_vector_type(4)));

#define AS_GLOBAL __attribute__((address_space(1)))
#define AS_LDS    __attribute__((address_space(3)))

__device__ __forceinline__ void gload_lds16(const void* g, void* l) {
    __builtin_amdgcn_global_load_lds((const AS_GLOBAL uint32_t*)g,
                                     (AS_LDS uint32_t*)l, 16, 0, 0);
}
__device__ __forceinline__ void cfence() { asm volatile("" ::: "memory"); }
#define BAR()    do { cfence(); __builtin_amdgcn_s_barrier(); cfence(); } while (0)
#define WAITV(n) asm volatile("s_waitcnt vmcnt(" #n ")" ::: "memory")
#define WAITL0() asm volatile("s_waitcnt lgkmcnt(0)" ::: "memory")

#define QSC 36.0f                            // q/k int8 scale
#define QDQ (1.0f / (QSC * QSC * 32.0f))     // logit dequant incl 1/sqrt(1024)

__device__ __forceinline__ int qi8(float f) {
    int q = (int)rintf(f);
    return q > 127 ? 127 : (q < -127 ? -127 : q);
}

// ---------------- convert fp32 -> bf16, 4 elems/thread ----------------
__global__ __launch_bounds__(256) void cvt_f32_to_bf16(const float* __restrict__ in,
                                                       bf16* __restrict__ out, int n4) {
    int i = blockIdx.x * 256 + threadIdx.x;
    if (i >= n4) return;
    const float4* p = (const float4*)in;
    float4 v = p[i];
    bf16x4 o;
    o[0] = (bf16)v.x; o[1] = (bf16)v.y; o[2] = (bf16)v.z; o[3] = (bf16)v.w;
    *(bf16x4*)(out + (size_t)i * 4) = o;
}

// ---------------- zero a float buffer, float4/thread ----------------
__global__ __launch_bounds__(256) void zero_f32v4(float* __restrict__ p, int n4) {
    int i = blockIdx.x * 256 + threadIdx.x;
    if (i < n4) ((float4*)p)[i] = make_float4(0.f, 0.f, 0.f, 0.f);
}

// ====== 2-window/K-tile bf16 GEMM (r7..r16 verified): C = A * B^T ======
// EPI=0: plain CT store (+split-K).
// EPI=1: QKV epilogue — panel 0 -> Qi8 (int8 x36), 1 -> Ki8,
//        2 -> VT DIRECT (in-LDS 256x256 transpose through dead smem, 2 halves).
// EPI=2: PV+normalize — atomicAdd(out, acc / sums[row]); out pre-zeroed;
//        deterministic (2 commutative f32 adds per element).
template<typename CT, int BN, int SPLIT, int EPI>
__global__ __launch_bounds__(512, 2) void gemmW(const bf16* __restrict__ A,
                                                const bf16* __restrict__ B,
                                                CT* __restrict__ C,
                                                CT* __restrict__ C2,
                                                int8_t* __restrict__ q8,
                                                int8_t* __restrict__ k8,
                                                bf16* __restrict__ vt,
                                                const float* __restrict__ sums,
                                                int K, int lda, int ldb, int ldc,
                                                int nbn) {
    constexpr int NBH = BN / 128;
    constexpr int NR  = BN / 64;
    constexpr int NHF = NR / 2;
    __shared__ char smem[65536 + NBH * 32768];

    const int tid  = threadIdx.x;
    const int lane = tid & 63;
    const int wave = tid >> 6;
    const int wr   = wave >> 2;
    const int wc   = wave & 3;
    const int frow = lane & 15;
    const int fg   = lane >> 4;

    const int cpx = gridDim.x >> 3;
    const int swz = ((int)blockIdx.x & 7) * cpx + ((int)blockIdx.x >> 3);
    int id = swz, s = 0;
    if (SPLIT == 2) { s = id & 1; id >>= 1; }
    const int bm = id / nbn, bn = id % nbn;
    const int NT = K >> 6;
    const size_t koff = (size_t)s * K;
    CT* Cp = (SPLIT == 2 && s == 1) ? C2 : C;

    const int r0 = tid >> 3;
    const int c0 = ((tid & 7) ^ (r0 & 7)) << 3;
    const bf16* Abase = A + (size_t)(bm * 256 + r0) * lda + c0 + koff;
    const bf16* Bbase = B + (size_t)(bn * BN + r0) * ldb + c0 + koff;

    auto stA = [&](int t, int h) {
        char* d = smem + ((t & 1) << 15) + (h << 14) + (tid << 4);
        gload_lds16(Abase + ((size_t)(h * 128)      ) * lda + t * 64, d);
        gload_lds16(Abase + ((size_t)(h * 128) + 64 ) * lda + t * 64, d + 8192);
    };
    auto stB = [&](int t, int h) {
        char* d = smem + 65536 + (t & 1) * (NBH * 16384) + (h << 14) + (tid << 4);
        gload_lds16(Bbase + ((size_t)(h * 128)      ) * ldb + t * 64, d);
        gload_lds16(Bbase + ((size_t)(h * 128) + 64 ) * ldb + t * 64, d + 8192);
    };
    auto rdA = [&](int t, int m, int kk) -> bf16x8 {
        int r = m * 16 + frow;
        return *(const bf16x8*)(smem + ((t & 1) << 15) + (wr << 14)
                + r * 128 + ((((kk << 2) + fg) ^ (frow & 7)) << 4));
    };
    auto rdB = [&](int t, int n, int kk) -> bf16x8 {
        int br = wc * (BN / 4) + n * 16 + frow;
        return *(const bf16x8*)(smem + 65536 + (t & 1) * (NBH * 16384) + ((br >> 7) << 14)
                + (br & 127) * 128 + ((((kk << 2) + fg) ^ (frow & 7)) << 4));
    };

    f32x4 acc[8][NR] = {};
    bf16x8 aLo[4][2], aHi[4][2], bLo[NHF][2], bHi[NHF][2];

#define MMQ(MO, NO, AARR, BARR) \
    _Pragma("unroll") for (int m_ = 0; m_ < 4; ++m_) \
    _Pragma("unroll") for (int n_ = 0; n_ < NHF; ++n_) \
    _Pragma("unroll") for (int k_ = 0; k_ < 2; ++k_) \
        acc[m_ + MO][n_ + NO] = __builtin_amdgcn_mfma_f32_16x16x32_bf16( \
            AARR[m_][k_], BARR[n_][k_], acc[m_ + MO][n_ + NO], 0, 0, 0);

    stA(0, 0); stA(0, 1);
    stB(0, 0); if constexpr (NBH == 2) stB(0, 1);
    stA(1, 0); stA(1, 1);
    if constexpr (NBH == 2) { stB(1, 0); WAITV(6); } else { WAITV(4); }
    BAR();

    for (int t = 0; t < NT; ++t) {
        if (t + 1 < NT) stB(t + 1, NBH - 1);
        #pragma unroll
        for (int m_ = 0; m_ < 4; ++m_) { aLo[m_][0] = rdA(t, m_, 0); aLo[m_][1] = rdA(t, m_, 1); }
        #pragma unroll
        for (int n_ = 0; n_ < NHF; ++n_) { bLo[n_][0] = rdB(t, n_, 0); bLo[n_][1] = rdB(t, n_, 1); }
        #pragma unroll
        for (int n_ = 0; n_ < NHF; ++n_) { bHi[n_][0] = rdB(t, NHF + n_, 0); bHi[n_][1] = rdB(t, NHF + n_, 1); }
        #pragma unroll
        for (int m_ = 0; m_ < 4; ++m_) { aHi[m_][0] = rdA(t, 4 + m_, 0); aHi[m_][1] = rdA(t, 4 + m_, 1); }
        __builtin_amdgcn_s_setprio(1);
        MMQ(0, 0, aLo, bLo);
        MMQ(0, NHF, aLo, bHi);
        __builtin_amdgcn_s_setprio(0);
        WAITL0();
        BAR();
        if (t + 2 < NT) {
            stA(t + 2, 0); stA(t + 2, 1);
            if constexpr (NBH == 2) stB(t + 2, 0);
        }
        __builtin_amdgcn_s_setprio(1);
        MMQ(4, NHF, aHi, bHi);
        MMQ(4, 0, aHi, bLo);
        __builtin_amdgcn_s_setprio(0);
        if (t + 2 < NT) {
            if constexpr (NBH == 2) WAITV(6); else WAITV(4);
        } else if (t + 1 < NT) {
            WAITV(0);
        }
        BAR();
    }
#undef MMQ

    const size_t crow0 = (size_t)bm * 256 + wr * 128 + (fg << 2);
    const size_t ccol0 = (size_t)bn * BN + wc * (BN / 4) + frow;
    if constexpr (EPI == 1) {
        const int panel = (int)(ccol0 >> 10);            // 0=Q, 1=K, 2=V
        const size_t pcol0 = ccol0 & 1023;
        if (panel < 2) {
            int8_t* dst = (panel == 0) ? q8 : k8;
            #pragma unroll
            for (int m = 0; m < 8; ++m)
                #pragma unroll
                for (int n = 0; n < NR; ++n)
                    #pragma unroll
                    for (int i = 0; i < 4; ++i)
                        dst[(crow0 + m * 16 + i) * 1024 + pcol0 + n * 16] =
                            (int8_t)qi8(acc[m][n][i] * QSC);
        } else {
            // V panel: in-LDS transpose (two 128-col halves), write VT[1024][8192]
            bf16* tl = (bf16*)smem;                      // [128][264] bf16 = 67.6 KB
            const int vcb  = (bn & 3) * 256;             // block's V col base
            const int lrow = wr * 128 + (fg << 2);       // local row base (+ m*16)
            #pragma unroll
            for (int h = 0; h < 2; ++h) {
                BAR();
                if ((wc >> 1) == h) {                    // wave-uniform branch
                    const int lc = (wc & 1) * 64 + frow; // 0..127 col within half
                    #pragma unroll
                    for (int m = 0; m < 8; ++m)
                        #pragma unroll
                        for (int n = 0; n < 4; ++n) {
                            bf16x4 v;
                            #pragma unroll
                            for (int i = 0; i < 4; ++i) v[i] = (bf16)acc[m][n][i];
                            *(bf16x4*)&tl[(lc + n * 16) * 264 + lrow + m * 16] = v;
                        }
                }
                BAR();
                // coalesced write out: lanes read consecutive 16B, rows contiguous
                #pragma unroll
                for (int j = 0; j < 8; ++j) {
                    int cid = j * 512 + tid;             // 0..4095
                    int c   = cid >> 5;                  // 0..127
                    int rc  = (cid & 31) << 3;           // 0..248
                    bf16x8 v = *(const bf16x8*)&tl[c * 264 + rc];
                    *(bf16x8*)&vt[(size_t)(vcb + h * 128 + c) * 8192 + bm * 256 + rc] = v;
                }
            }
        }
    } else if constexpr (EPI == 2) {
        // normalize + accumulate: out pre-zeroed, 2 commutative adds/element
        #pragma unroll
        for (int m = 0; m < 8; ++m)
            #pragma unroll
            for (int i = 0; i < 4; ++i) {
                const size_t row = crow0 + m * 16 + i;
                const float inv = 1.0f / sums[row];
                #pragma unroll
                for (int n = 0; n < NR; ++n)
                    atomicAdd((float*)&C[row * ldc + ccol0 + n * 16],
                              acc[m][n][i] * inv);
            }
    } else {
        #pragma unroll
        for (int m = 0; m < 8; ++m)
            #pragma unroll
            for (int n = 0; n < NR; ++n)
                #pragma unroll
                for (int i = 0; i < 4; ++i)
                    Cp[(crow0 + m * 16 + i) * ldc + ccol0 + n * 16] = (CT)(acc[m][n][i]);
    }
}

// ====== int8 QK^T -> bf16 E = exp(acc/41472) + fused LDS row-sums (r16 verified) ======
__global__ __launch_bounds__(512, 2) void gemmEi8(const int8_t* __restrict__ A,
                                                  const int8_t* __restrict__ B,
                                                  bf16* __restrict__ E,
                                                  float* __restrict__ sums,
                                                  int K, int ld, int ldc, int nbn) {
    __shared__ char smem[131072];   // A dbuf 2x32KB @0 | B dbuf 2x32KB @65536

    const int tid  = threadIdx.x;
    const int lane = tid & 63;
    const int wave = tid >> 6;
    const int wr   = wave >> 2;           // 0..1
    const int wc   = wave & 3;            // 0..3
    const int frow = lane & 15;
    const int fg   = lane >> 4;           // 0..3

    const int cpx = gridDim.x >> 3;
    const int swz = ((int)blockIdx.x & 7) * cpx + ((int)blockIdx.x >> 3);
    const int bm = swz / nbn, bn = swz % nbn;
    const int NT = K >> 7;                // 8

    const int r0 = tid >> 3;
    const int c0 = ((tid & 7) ^ (r0 & 7)) << 4;     // inv-swizzled byte col
    const int8_t* Abase = A + (size_t)(bm * 256 + r0) * ld + c0;
    const int8_t* Bbase = B + (size_t)(bn * 256 + r0) * ld + c0;

    auto stA = [&](int t, int h) {
        char* d = smem + ((t & 1) << 15) + (h << 14) + (tid << 4);
        gload_lds16(Abase + ((size_t)(h * 128)     ) * ld + t * 128, d);
        gload_lds16(Abase + ((size_t)(h * 128) + 64) * ld + t * 128, d + 8192);
    };
    auto stB = [&](int t, int h) {
        char* d = smem + 65536 + ((t & 1) << 15) + (h << 14) + (tid << 4);
        gload_lds16(Bbase + ((size_t)(h * 128)     ) * ld + t * 128, d);
        gload_lds16(Bbase + ((size_t)(h * 128) + 64) * ld + t * 128, d + 8192);
    };
    auto rdA = [&](int t, int m, int kk) -> i32x4 {   // m in [0,8)
        int r = m * 16 + frow;
        return *(const i32x4*)(smem + ((t & 1) << 15) + (wr << 14)
                + r * 128 + ((((kk << 2) + fg) ^ (frow & 7)) << 4));
    };
    auto rdB = [&](int t, int n, int kk) -> i32x4 {   // n in [0,4)
        int br = wc * 64 + n * 16 + frow;
        return *(const i32x4*)(smem + 65536 + ((t & 1) << 15) + ((br >> 7) << 14)
                + (br & 127) * 128 + ((((kk << 2) + fg) ^ (frow & 7)) << 4));
    };

    i32x4 acc[8][4] = {};
    i32x4 aLo[4][2], aHi[4][2], bLo[2][2], bHi[2][2];

#define MMQ(MO, NO, AARR, BARR) \
    _Pragma("unroll") for (int m_ = 0; m_ < 4; ++m_) \
    _Pragma("unroll") for (int n_ = 0; n_ < 2; ++n_) \
    _Pragma("unroll") for (int k_ = 0; k_ < 2; ++k_) \
        acc[m_ + MO][n_ + NO] = __builtin_amdgcn_mfma_i32_16x16x64_i8( \
            AARR[m_][k_], BARR[n_][k_], acc[m_ + MO][n_ + NO], 0, 0, 0);

    stA(0, 0); stA(0, 1);
    stB(0, 0); stB(0, 1);
    stA(1, 0); stA(1, 1);
    stB(1, 0); WAITV(6);
    BAR();

    for (int t = 0; t < NT; ++t) {
        if (t + 1 < NT) stB(t + 1, 1);
        #pragma unroll
        for (int m_ = 0; m_ < 4; ++m_) { aLo[m_][0] = rdA(t, m_, 0); aLo[m_][1] = rdA(t, m_, 1); }
        #pragma unroll
        for (int n_ = 0; n_ < 2; ++n_) { bLo[n_][0] = rdB(t, n_, 0); bLo[n_][1] = rdB(t, n_, 1); }
        #pragma unroll
        for (int n_ = 0; n_ < 2; ++n_) { bHi[n_][0] = rdB(t, 2 + n_, 0); bHi[n_][1] = rdB(t, 2 + n_, 1); }
        #pragma unroll
        for (int m_ = 0; m_ < 4; ++m_) { aHi[m_][0] = rdA(t, 4 + m_, 0); aHi[m_][1] = rdA(t, 4 + m_, 1); }
        __builtin_amdgcn_s_setprio(1);
        MMQ(0, 0, aLo, bLo);
        MMQ(0, 2, aLo, bHi);
        __builtin_amdgcn_s_setprio(0);
        WAITL0();
        BAR();
        if (t + 2 < NT) { stA(t + 2, 0); stA(t + 2, 1); stB(t + 2, 0); }
        __builtin_amdgcn_s_setprio(1);
        MMQ(4, 2, aHi, bHi);
        MMQ(4, 0, aHi, bLo);
        __builtin_amdgcn_s_setprio(0);
        if (t + 2 < NT)      { WAITV(6); }
        else if (t + 1 < NT) { WAITV(0); }
        BAR();
    }
#undef MMQ

    // epilogue: E = exp(acc * QDQ) + LDS row-partial reduction (r16 verified)
    const size_t crow0 = (size_t)bm * 256 + wr * 128 + (fg << 2);
    const size_t ccol0 = (size_t)bn * 256 + wc * 64 + frow;
    float* part = (float*)smem;                 // [256][66] floats
    const int rl0 = wr * 128 + (fg << 2);
    const int ent = wc * 16 + frow;
    #pragma unroll
    for (int m = 0; m < 8; ++m)
        #pragma unroll
        for (int i = 0; i < 4; ++i) {
            float s = 0.f;
            #pragma unroll
            for (int n = 0; n < 4; ++n) {
                float e = __expf((float)acc[m][n][i] * QDQ);
                bf16 b = (bf16)e;
                E[(crow0 + m * 16 + i) * ldc + ccol0 + n * 16] = b;
                s += (float)b;
            }
            part[(rl0 + m * 16 + i) * 66 + ent] = s;
        }
    __syncthreads();
    if (tid < 256) {
        float s = 0.f;
        const float* pr = part + tid * 66;
        #pragma unroll 8
        for (int e = 0; e < 64; ++e) s += pr[e];
        atomicAdd(&sums[(size_t)bm * 256 + tid], s);
    }
}

extern "C" void kernel_launch(void* const* d_in, const int* in_sizes, int n_in,
                              void* d_out, int out_size, void* d_ws, size_t ws_size,
                              hipStream_t stream) {
    const float* h  = (const float*)d_in[0];
    const float* wq = (const float*)d_in[1];
    const float* wk = (const float*)d_in[2];
    const float* wv = (const float*)d_in[3];
    float* out = (float*)d_out;

    char* ws = (char*)d_ws;
    bf16*   h_bf = (bf16*)(ws);                         // 16 MB [8192 x 1024]
    bf16*   wcat = (bf16*)(ws + (16ull << 20));         //  6 MB [3072 x 1024]
    int8_t* Qi8  = (int8_t*)(ws + (22ull << 20));       //  8 MB [8192 x 1024]
    int8_t* Ki8  = (int8_t*)(ws + (30ull << 20));       //  8 MB
    bf16*   VT   = (bf16*)(ws + (38ull << 20));         // 16 MB [1024 x 8192]
    bf16*   E    = (bf16*)(ws + (54ull << 20));         // 128 MB [8192 x 8192]
    float*  sums = (float*)(ws + (182ull << 20));       // 32 KB

    // 1) inputs -> bf16; zero sums and out
    cvt_f32_to_bf16<<<8192, 256, 0, stream>>>(h,  h_bf, (8192 * 1024) / 4);
    cvt_f32_to_bf16<<<1024, 256, 0, stream>>>(wq, wcat,               (1024 * 1024) / 4);
    cvt_f32_to_bf16<<<1024, 256, 0, stream>>>(wk, wcat + 1024 * 1024, (1024 * 1024) / 4);
    cvt_f32_to_bf16<<<1024, 256, 0, stream>>>(wv, wcat + 2048 * 1024, (1024 * 1024) / 4);
    zero_f32v4<<<8, 256, 0, stream>>>(sums, 8192 / 4);
    zero_f32v4<<<8192, 256, 0, stream>>>(out, (8192 * 1024) / 4);

    // 2) fused QKV projection: Q,K -> int8, V -> VT direct (in-LDS transpose), grid 384
    gemmW<bf16, 256, 1, 1><<<384, 512, 0, stream>>>(h_bf, wcat, nullptr, nullptr,
                                                    Qi8, Ki8, VT, nullptr,
                                                    1024, 1024, 1024, 1024, 12);

    // 3) E = exp((Qi8 . Ki8)/41472) + fused LDS row-sums, grid 1024
    gemmEi8<<<1024, 512, 0, stream>>>(Qi8, Ki8, E, sums, 1024, 1024, 8192, 32);

    // 4) out += (E @ VT^T) / sums[row], split-K=2 atomic epilogue, grid 256
    gemmW<float, 256, 2, 2><<<256, 512, 0, stream>>>(E, VT, out, nullptr,
                                                     nullptr, nullptr, nullptr, sums,
                                                     4096, 8192, 8192, 1024, 4);
}

// Round 18
// 301.796 us; speedup vs baseline: 1.1026x; 1.1026x over previous
//
#include <hip/hip_runtime.h>
#include <hip/hip_bf16.h>
#include <stdint.h>
#include <math.h>

typedef __bf16 bf16;
typedef __bf16 bf16x8 __attribute__((ext_vector_type(8)));
typedef __bf16 bf16x4 __attribute__((ext_vector_type(4)));
typedef float  f32x4  __attribute__((ext_vector_type(4)));
typedef int    i32x4  __attribute__((ext_vector_type(4)));

#define AS_GLOBAL __attribute__((address_space(1)))
#define AS_LDS    __attribute__((address_space(3)))

__device__ __forceinline__ void gload_lds16(const void* g, void* l) {
    __builtin_amdgcn_global_load_lds((const AS_GLOBAL uint32_t*)g,
                                     (AS_LDS uint32_t*)l, 16, 0, 0);
}
__device__ __forceinline__ void cfence() { asm volatile("" ::: "memory"); }
#define BAR()    do { cfence(); __builtin_amdgcn_s_barrier(); cfence(); } while (0)
#define WAITV(n) asm volatile("s_waitcnt vmcnt(" #n ")" ::: "memory")
#define WAITL0() asm volatile("s_waitcnt lgkmcnt(0)" ::: "memory")

#define QSC 36.0f                            // q/k int8 scale
#define QDQ (1.0f / (QSC * QSC * 32.0f))     // logit dequant incl 1/sqrt(1024)

__device__ __forceinline__ int qi8(float f) {
    int q = (int)rintf(f);
    return q > 127 ? 127 : (q < -127 ? -127 : q);
}

// ---------------- convert fp32 -> bf16, 4 elems/thread ----------------
__global__ __launch_bounds__(256) void cvt_f32_to_bf16(const float* __restrict__ in,
                                                       bf16* __restrict__ out, int n4) {
    int i = blockIdx.x * 256 + threadIdx.x;
    if (i >= n4) return;
    const float4* p = (const float4*)in;
    float4 v = p[i];
    bf16x4 o;
    o[0] = (bf16)v.x; o[1] = (bf16)v.y; o[2] = (bf16)v.z; o[3] = (bf16)v.w;
    *(bf16x4*)(out + (size_t)i * 4) = o;
}

// ---------------- zero a float buffer, float4/thread ----------------
__global__ __launch_bounds__(256) void zero_f32v4(float* __restrict__ p, int n4) {
    int i = blockIdx.x * 256 + threadIdx.x;
    if (i < n4) ((float4*)p)[i] = make_float4(0.f, 0.f, 0.f, 0.f);
}

// ====== 2-window/K-tile bf16 GEMM (r7..r17 verified): C = A * B^T ======
// EPI=0: plain CT store (+split-K)  [PV: 124 µs, 46% MfmaUtil, r16]
// EPI=1: QKV epilogue — panel 0 -> Qi8 (x36), 1 -> Ki8, 2 -> VT direct
//        (in-LDS transpose, r17-verified).  NOTE r17 lesson: NO atomic
//        epilogue (EPI=2 cost +37 µs: 128 scattered L2-RMW adds/thread).
template<typename CT, int BN, int SPLIT, int EPI>
__global__ __launch_bounds__(512, 2) void gemmW(const bf16* __restrict__ A,
                                                const bf16* __restrict__ B,
                                                CT* __restrict__ C,
                                                CT* __restrict__ C2,
                                                int8_t* __restrict__ q8,
                                                int8_t* __restrict__ k8,
                                                bf16* __restrict__ vt,
                                                int K, int lda, int ldb, int ldc,
                                                int nbn) {
    constexpr int NBH = BN / 128;
    constexpr int NR  = BN / 64;
    constexpr int NHF = NR / 2;
    __shared__ char smem[65536 + NBH * 32768];

    const int tid  = threadIdx.x;
    const int lane = tid & 63;
    const int wave = tid >> 6;
    const int wr   = wave >> 2;
    const int wc   = wave & 3;
    const int frow = lane & 15;
    const int fg   = lane >> 4;

    const int cpx = gridDim.x >> 3;
    const int swz = ((int)blockIdx.x & 7) * cpx + ((int)blockIdx.x >> 3);
    int id = swz, s = 0;
    if (SPLIT == 2) { s = id & 1; id >>= 1; }
    const int bm = id / nbn, bn = id % nbn;
    const int NT = K >> 6;
    const size_t koff = (size_t)s * K;
    CT* Cp = (SPLIT == 2 && s == 1) ? C2 : C;

    const int r0 = tid >> 3;
    const int c0 = ((tid & 7) ^ (r0 & 7)) << 3;
    const bf16* Abase = A + (size_t)(bm * 256 + r0) * lda + c0 + koff;
    const bf16* Bbase = B + (size_t)(bn * BN + r0) * ldb + c0 + koff;

    auto stA = [&](int t, int h) {
        char* d = smem + ((t & 1) << 15) + (h << 14) + (tid << 4);
        gload_lds16(Abase + ((size_t)(h * 128)      ) * lda + t * 64, d);
        gload_lds16(Abase + ((size_t)(h * 128) + 64 ) * lda + t * 64, d + 8192);
    };
    auto stB = [&](int t, int h) {
        char* d = smem + 65536 + (t & 1) * (NBH * 16384) + (h << 14) + (tid << 4);
        gload_lds16(Bbase + ((size_t)(h * 128)      ) * ldb + t * 64, d);
        gload_lds16(Bbase + ((size_t)(h * 128) + 64 ) * ldb + t * 64, d + 8192);
    };
    auto rdA = [&](int t, int m, int kk) -> bf16x8 {
        int r = m * 16 + frow;
        return *(const bf16x8*)(smem + ((t & 1) << 15) + (wr << 14)
                + r * 128 + ((((kk << 2) + fg) ^ (frow & 7)) << 4));
    };
    auto rdB = [&](int t, int n, int kk) -> bf16x8 {
        int br = wc * (BN / 4) + n * 16 + frow;
        return *(const bf16x8*)(smem + 65536 + (t & 1) * (NBH * 16384) + ((br >> 7) << 14)
                + (br & 127) * 128 + ((((kk << 2) + fg) ^ (frow & 7)) << 4));
    };

    f32x4 acc[8][NR] = {};
    bf16x8 aLo[4][2], aHi[4][2], bLo[NHF][2], bHi[NHF][2];

#define MMQ(MO, NO, AARR, BARR) \
    _Pragma("unroll") for (int m_ = 0; m_ < 4; ++m_) \
    _Pragma("unroll") for (int n_ = 0; n_ < NHF; ++n_) \
    _Pragma("unroll") for (int k_ = 0; k_ < 2; ++k_) \
        acc[m_ + MO][n_ + NO] = __builtin_amdgcn_mfma_f32_16x16x32_bf16( \
            AARR[m_][k_], BARR[n_][k_], acc[m_ + MO][n_ + NO], 0, 0, 0);

    stA(0, 0); stA(0, 1);
    stB(0, 0); if constexpr (NBH == 2) stB(0, 1);
    stA(1, 0); stA(1, 1);
    if constexpr (NBH == 2) { stB(1, 0); WAITV(6); } else { WAITV(4); }
    BAR();

    for (int t = 0; t < NT; ++t) {
        if (t + 1 < NT) stB(t + 1, NBH - 1);
        #pragma unroll
        for (int m_ = 0; m_ < 4; ++m_) { aLo[m_][0] = rdA(t, m_, 0); aLo[m_][1] = rdA(t, m_, 1); }
        #pragma unroll
        for (int n_ = 0; n_ < NHF; ++n_) { bLo[n_][0] = rdB(t, n_, 0); bLo[n_][1] = rdB(t, n_, 1); }
        #pragma unroll
        for (int n_ = 0; n_ < NHF; ++n_) { bHi[n_][0] = rdB(t, NHF + n_, 0); bHi[n_][1] = rdB(t, NHF + n_, 1); }
        #pragma unroll
        for (int m_ = 0; m_ < 4; ++m_) { aHi[m_][0] = rdA(t, 4 + m_, 0); aHi[m_][1] = rdA(t, 4 + m_, 1); }
        __builtin_amdgcn_s_setprio(1);
        MMQ(0, 0, aLo, bLo);
        MMQ(0, NHF, aLo, bHi);
        __builtin_amdgcn_s_setprio(0);
        WAITL0();
        BAR();
        if (t + 2 < NT) {
            stA(t + 2, 0); stA(t + 2, 1);
            if constexpr (NBH == 2) stB(t + 2, 0);
        }
        __builtin_amdgcn_s_setprio(1);
        MMQ(4, NHF, aHi, bHi);
        MMQ(4, 0, aHi, bLo);
        __builtin_amdgcn_s_setprio(0);
        if (t + 2 < NT) {
            if constexpr (NBH == 2) WAITV(6); else WAITV(4);
        } else if (t + 1 < NT) {
            WAITV(0);
        }
        BAR();
    }
#undef MMQ

    const size_t crow0 = (size_t)bm * 256 + wr * 128 + (fg << 2);
    const size_t ccol0 = (size_t)bn * BN + wc * (BN / 4) + frow;
    if constexpr (EPI == 1) {
        const int panel = (int)(ccol0 >> 10);            // 0=Q, 1=K, 2=V
        const size_t pcol0 = ccol0 & 1023;
        if (panel < 2) {
            int8_t* dst = (panel == 0) ? q8 : k8;
            #pragma unroll
            for (int m = 0; m < 8; ++m)
                #pragma unroll
                for (int n = 0; n < NR; ++n)
                    #pragma unroll
                    for (int i = 0; i < 4; ++i)
                        dst[(crow0 + m * 16 + i) * 1024 + pcol0 + n * 16] =
                            (int8_t)qi8(acc[m][n][i] * QSC);
        } else {
            // V panel: in-LDS transpose (two 128-col halves), write VT[1024][8192]
            bf16* tl = (bf16*)smem;                      // [128][264] bf16
            const int vcb  = (bn & 3) * 256;             // block's V col base
            const int lrow = wr * 128 + (fg << 2);       // local row base (+ m*16)
            #pragma unroll
            for (int h = 0; h < 2; ++h) {
                BAR();
                if ((wc >> 1) == h) {                    // wave-uniform branch
                    const int lc = (wc & 1) * 64 + frow; // col within half
                    #pragma unroll
                    for (int m = 0; m < 8; ++m)
                        #pragma unroll
                        for (int n = 0; n < 4; ++n) {
                            bf16x4 v;
                            #pragma unroll
                            for (int i = 0; i < 4; ++i) v[i] = (bf16)acc[m][n][i];
                            *(bf16x4*)&tl[(lc + n * 16) * 264 + lrow + m * 16] = v;
                        }
                }
                BAR();
                #pragma unroll
                for (int j = 0; j < 8; ++j) {
                    int cid = j * 512 + tid;             // 0..4095
                    int c   = cid >> 5;                  // 0..127
                    int rc  = (cid & 31) << 3;           // 0..248
                    bf16x8 v = *(const bf16x8*)&tl[c * 264 + rc];
                    *(bf16x8*)&vt[(size_t)(vcb + h * 128 + c) * 8192 + bm * 256 + rc] = v;
                }
            }
        }
    } else {
        #pragma unroll
        for (int m = 0; m < 8; ++m)
            #pragma unroll
            for (int n = 0; n < NR; ++n)
                #pragma unroll
                for (int i = 0; i < 4; ++i)
                    Cp[(crow0 + m * 16 + i) * ldc + ccol0 + n * 16] = (CT)(acc[m][n][i]);
    }
}

// ====== int8 QK^T -> bf16 E = exp(acc/41472) + fused LDS row-sums (r16 verified) ======
__global__ __launch_bounds__(512, 2) void gemmEi8(const int8_t* __restrict__ A,
                                                  const int8_t* __restrict__ B,
                                                  bf16* __restrict__ E,
                                                  float* __restrict__ sums,
                                                  int K, int ld, int ldc, int nbn) {
    __shared__ char smem[131072];   // A dbuf 2x32KB @0 | B dbuf 2x32KB @65536

    const int tid  = threadIdx.x;
    const int lane = tid & 63;
    const int wave = tid >> 6;
    const int wr   = wave >> 2;           // 0..1
    const int wc   = wave & 3;            // 0..3
    const int frow = lane & 15;
    const int fg   = lane >> 4;           // 0..3

    const int cpx = gridDim.x >> 3;
    const int swz = ((int)blockIdx.x & 7) * cpx + ((int)blockIdx.x >> 3);
    const int bm = swz / nbn, bn = swz % nbn;
    const int NT = K >> 7;                // 8

    const int r0 = tid >> 3;
    const int c0 = ((tid & 7) ^ (r0 & 7)) << 4;     // inv-swizzled byte col
    const int8_t* Abase = A + (size_t)(bm * 256 + r0) * ld + c0;
    const int8_t* Bbase = B + (size_t)(bn * 256 + r0) * ld + c0;

    auto stA = [&](int t, int h) {
        char* d = smem + ((t & 1) << 15) + (h << 14) + (tid << 4);
        gload_lds16(Abase + ((size_t)(h * 128)     ) * ld + t * 128, d);
        gload_lds16(Abase + ((size_t)(h * 128) + 64) * ld + t * 128, d + 8192);
    };
    auto stB = [&](int t, int h) {
        char* d = smem + 65536 + ((t & 1) << 15) + (h << 14) + (tid << 4);
        gload_lds16(Bbase + ((size_t)(h * 128)     ) * ld + t * 128, d);
        gload_lds16(Bbase + ((size_t)(h * 128) + 64) * ld + t * 128, d + 8192);
    };
    auto rdA = [&](int t, int m, int kk) -> i32x4 {   // m in [0,8)
        int r = m * 16 + frow;
        return *(const i32x4*)(smem + ((t & 1) << 15) + (wr << 14)
                + r * 128 + ((((kk << 2) + fg) ^ (frow & 7)) << 4));
    };
    auto rdB = [&](int t, int n, int kk) -> i32x4 {   // n in [0,4)
        int br = wc * 64 + n * 16 + frow;
        return *(const i32x4*)(smem + 65536 + ((t & 1) << 15) + ((br >> 7) << 14)
                + (br & 127) * 128 + ((((kk << 2) + fg) ^ (frow & 7)) << 4));
    };

    i32x4 acc[8][4] = {};
    i32x4 aLo[4][2], aHi[4][2], bLo[2][2], bHi[2][2];

#define MMQ(MO, NO, AARR, BARR) \
    _Pragma("unroll") for (int m_ = 0; m_ < 4; ++m_) \
    _Pragma("unroll") for (int n_ = 0; n_ < 2; ++n_) \
    _Pragma("unroll") for (int k_ = 0; k_ < 2; ++k_) \
        acc[m_ + MO][n_ + NO] = __builtin_amdgcn_mfma_i32_16x16x64_i8( \
            AARR[m_][k_], BARR[n_][k_], acc[m_ + MO][n_ + NO], 0, 0, 0);

    stA(0, 0); stA(0, 1);
    stB(0, 0); stB(0, 1);
    stA(1, 0); stA(1, 1);
    stB(1, 0); WAITV(6);
    BAR();

    for (int t = 0; t < NT; ++t) {
        if (t + 1 < NT) stB(t + 1, 1);
        #pragma unroll
        for (int m_ = 0; m_ < 4; ++m_) { aLo[m_][0] = rdA(t, m_, 0); aLo[m_][1] = rdA(t, m_, 1); }
        #pragma unroll
        for (int n_ = 0; n_ < 2; ++n_) { bLo[n_][0] = rdB(t, n_, 0); bLo[n_][1] = rdB(t, n_, 1); }
        #pragma unroll
        for (int n_ = 0; n_ < 2; ++n_) { bHi[n_][0] = rdB(t, 2 + n_, 0); bHi[n_][1] = rdB(t, 2 + n_, 1); }
        #pragma unroll
        for (int m_ = 0; m_ < 4; ++m_) { aHi[m_][0] = rdA(t, 4 + m_, 0); aHi[m_][1] = rdA(t, 4 + m_, 1); }
        __builtin_amdgcn_s_setprio(1);
        MMQ(0, 0, aLo, bLo);
        MMQ(0, 2, aLo, bHi);
        __builtin_amdgcn_s_setprio(0);
        WAITL0();
        BAR();
        if (t + 2 < NT) { stA(t + 2, 0); stA(t + 2, 1); stB(t + 2, 0); }
        __builtin_amdgcn_s_setprio(1);
        MMQ(4, 2, aHi, bHi);
        MMQ(4, 0, aHi, bLo);
        __builtin_amdgcn_s_setprio(0);
        if (t + 2 < NT)      { WAITV(6); }
        else if (t + 1 < NT) { WAITV(0); }
        BAR();
    }
#undef MMQ

    // epilogue: E = exp(acc * QDQ) + LDS row-partial reduction (r16 verified)
    const size_t crow0 = (size_t)bm * 256 + wr * 128 + (fg << 2);
    const size_t ccol0 = (size_t)bn * 256 + wc * 64 + frow;
    float* part = (float*)smem;                 // [256][66] floats
    const int rl0 = wr * 128 + (fg << 2);
    const int ent = wc * 16 + frow;
    #pragma unroll
    for (int m = 0; m < 8; ++m)
        #pragma unroll
        for (int i = 0; i < 4; ++i) {
            float s = 0.f;
            #pragma unroll
            for (int n = 0; n < 4; ++n) {
                float e = __expf((float)acc[m][n][i] * QDQ);
                bf16 b = (bf16)e;
                E[(crow0 + m * 16 + i) * ldc + ccol0 + n * 16] = b;
                s += (float)b;
            }
            part[(rl0 + m * 16 + i) * 66 + ent] = s;
        }
    __syncthreads();
    if (tid < 256) {
        float s = 0.f;
        const float* pr = part + tid * 66;
        #pragma unroll 8
        for (int e = 0; e < 64; ++e) s += pr[e];
        atomicAdd(&sums[(size_t)bm * 256 + tid], s);
    }
}

// ------- out[i] = (out[i] + part[i]) / sums[row], float4 -------
__global__ __launch_bounds__(256) void add_scale(float* __restrict__ out,
                                                 const float* __restrict__ part,
                                                 const float* __restrict__ sums, int n4) {
    int i = blockIdx.x * 256 + threadIdx.x;
    if (i >= n4) return;
    const float sc = 1.0f / sums[i >> 8];
    float4 a = ((const float4*)out)[i];
    float4 b = ((const float4*)part)[i];
    a.x = (a.x + b.x) * sc; a.y = (a.y + b.y) * sc;
    a.z = (a.z + b.z) * sc; a.w = (a.w + b.w) * sc;
    ((float4*)out)[i] = a;
}

extern "C" void kernel_launch(void* const* d_in, const int* in_sizes, int n_in,
                              void* d_out, int out_size, void* d_ws, size_t ws_size,
                              hipStream_t stream) {
    const float* h  = (const float*)d_in[0];
    const float* wq = (const float*)d_in[1];
    const float* wk = (const float*)d_in[2];
    const float* wv = (const float*)d_in[3];
    float* out = (float*)d_out;

    char* ws = (char*)d_ws;
    bf16*   h_bf = (bf16*)(ws);                         // 16 MB [8192 x 1024]
    bf16*   wcat = (bf16*)(ws + (16ull << 20));         //  6 MB [3072 x 1024]
    int8_t* Qi8  = (int8_t*)(ws + (22ull << 20));       //  8 MB [8192 x 1024]
    int8_t* Ki8  = (int8_t*)(ws + (30ull << 20));       //  8 MB
    bf16*   VT   = (bf16*)(ws + (38ull << 20));         // 16 MB [1024 x 8192]
    bf16*   E    = (bf16*)(ws + (54ull << 20));         // 128 MB [8192 x 8192]
    float*  sums = (float*)(ws + (182ull << 20));       // 32 KB
    float*  Pv   = (float*)(ws);                        // 32 MB (h_bf..Ki8 dead by PV)

    // 1) inputs -> bf16; zero sums
    cvt_f32_to_bf16<<<8192, 256, 0, stream>>>(h,  h_bf, (8192 * 1024) / 4);
    cvt_f32_to_bf16<<<1024, 256, 0, stream>>>(wq, wcat,               (1024 * 1024) / 4);
    cvt_f32_to_bf16<<<1024, 256, 0, stream>>>(wk, wcat + 1024 * 1024, (1024 * 1024) / 4);
    cvt_f32_to_bf16<<<1024, 256, 0, stream>>>(wv, wcat + 2048 * 1024, (1024 * 1024) / 4);
    zero_f32v4<<<8, 256, 0, stream>>>(sums, 8192 / 4);

    // 2) fused QKV projection: Q,K -> int8, V -> VT direct (in-LDS transpose), grid 384
    gemmW<bf16, 256, 1, 1><<<384, 512, 0, stream>>>(h_bf, wcat, nullptr, nullptr,
                                                    Qi8, Ki8, VT,
                                                    1024, 1024, 1024, 1024, 12);

    // 3) E = exp((Qi8 . Ki8)/41472) + fused LDS row-sums, grid 1024
    gemmEi8<<<1024, 512, 0, stream>>>(Qi8, Ki8, E, sums, 1024, 1024, 8192, 32);

    // 4) P = E @ VT^T, plain split-K=2 stores (r16-proven), grid 256
    gemmW<float, 256, 2, 0><<<256, 512, 0, stream>>>(E, VT, out, Pv,
                                                     nullptr, nullptr, nullptr,
                                                     4096, 8192, 8192, 1024, 4);

    // 5) out = (P0 + P1) / sums[row]
    add_scale<<<8192, 256, 0, stream>>>(out, Pv, sums, (8192 * 1024) / 4);
}

// Round 19
// 295.690 us; speedup vs baseline: 1.1254x; 1.0206x over previous
//
#include <hip/hip_runtime.h>
#include <hip/hip_bf16.h>
#include <stdint.h>
#include <math.h>

typedef __bf16 bf16;
typedef __bf16 bf16x8 __attribute__((ext_vector_type(8)));
typedef __bf16 bf16x4 __attribute__((ext_vector_type(4)));
typedef float  f32x4  __attribute__((ext_vector_type(4)));
typedef int    i32x4  __attribute__((ext_vector_type(4)));

#define AS_GLOBAL __attribute__((address_space(1)))
#define AS_LDS    __attribute__((address_space(3)))

__device__ __forceinline__ void gload_lds16(const void* g, void* l) {
    __builtin_amdgcn_global_load_lds((const AS_GLOBAL uint32_t*)g,
                                     (AS_LDS uint32_t*)l, 16, 0, 0);
}
__device__ __forceinline__ void cfence() { asm volatile("" ::: "memory"); }
#define BAR()    do { cfence(); __builtin_amdgcn_s_barrier(); cfence(); } while (0)
#define WAITV(n) asm volatile("s_waitcnt vmcnt(" #n ")" ::: "memory")
#define WAITL0() asm volatile("s_waitcnt lgkmcnt(0)" ::: "memory")

#define QSC 36.0f                            // q/k int8 scale
#define QDQ (1.0f / (QSC * QSC * 32.0f))     // logit dequant incl 1/sqrt(1024)

__device__ __forceinline__ int qi8(float f) {
    int q = (int)rintf(f);
    return q > 127 ? 127 : (q < -127 ? -127 : q);
}

// ---- fused prep: h->bf16 (8192 blk), wq/wk/wv->wcat (3x1024 blk), zero sums (8 blk) ----
__global__ __launch_bounds__(256) void prep(const float* __restrict__ h,
                                            const float* __restrict__ wq,
                                            const float* __restrict__ wk,
                                            const float* __restrict__ wv,
                                            bf16* __restrict__ h_bf,
                                            bf16* __restrict__ wcat,
                                            float* __restrict__ sums) {
    const int b = blockIdx.x;
    if (b < 11264) {
        const float* src;
        bf16* dst;
        int i;
        if (b < 8192)      { src = h;  dst = h_bf;                i = b * 256 + threadIdx.x; }
        else if (b < 9216) { src = wq; dst = wcat;                i = (b - 8192) * 256 + threadIdx.x; }
        else if (b < 10240){ src = wk; dst = wcat + 1024 * 1024;  i = (b - 9216) * 256 + threadIdx.x; }
        else               { src = wv; dst = wcat + 2048 * 1024;  i = (b - 10240) * 256 + threadIdx.x; }
        float4 v = ((const float4*)src)[i];
        bf16x4 o;
        o[0] = (bf16)v.x; o[1] = (bf16)v.y; o[2] = (bf16)v.z; o[3] = (bf16)v.w;
        *(bf16x4*)(dst + (size_t)i * 4) = o;
    } else {
        int i = (b - 11264) * 256 + threadIdx.x;
        if (i < 2048) ((float4*)sums)[i] = make_float4(0.f, 0.f, 0.f, 0.f);
    }
}

// ====== 2-window/K-tile bf16 GEMM (r7..r18 verified): C = A * B^T ======
// EPI=0: plain CT store (+split-K)  [PV: 124 µs, 46% MfmaUtil]
// EPI=1: QKV epilogue — panel 0 -> Qi8 (x36), 1 -> Ki8, 2 -> VT direct
//        (in-LDS transpose).  r17 lesson: NO atomic epilogue (+37 µs L2-RMW).
template<typename CT, int BN, int SPLIT, int EPI>
__global__ __launch_bounds__(512, 2) void gemmW(const bf16* __restrict__ A,
                                                const bf16* __restrict__ B,
                                                CT* __restrict__ C,
                                                CT* __restrict__ C2,
                                                int8_t* __restrict__ q8,
                                                int8_t* __restrict__ k8,
                                                bf16* __restrict__ vt,
                                                int K, int lda, int ldb, int ldc,
                                                int nbn) {
    constexpr int NBH = BN / 128;
    constexpr int NR  = BN / 64;
    constexpr int NHF = NR / 2;
    __shared__ char smem[65536 + NBH * 32768];

    const int tid  = threadIdx.x;
    const int lane = tid & 63;
    const int wave = tid >> 6;
    const int wr   = wave >> 2;
    const int wc   = wave & 3;
    const int frow = lane & 15;
    const int fg   = lane >> 4;

    const int cpx = gridDim.x >> 3;
    const int swz = ((int)blockIdx.x & 7) * cpx + ((int)blockIdx.x >> 3);
    int id = swz, s = 0;
    if (SPLIT == 2) { s = id & 1; id >>= 1; }
    const int bm = id / nbn, bn = id % nbn;
    const int NT = K >> 6;
    const size_t koff = (size_t)s * K;
    CT* Cp = (SPLIT == 2 && s == 1) ? C2 : C;

    const int r0 = tid >> 3;
    const int c0 = ((tid & 7) ^ (r0 & 7)) << 3;
    const bf16* Abase = A + (size_t)(bm * 256 + r0) * lda + c0 + koff;
    const bf16* Bbase = B + (size_t)(bn * BN + r0) * ldb + c0 + koff;

    auto stA = [&](int t, int h) {
        char* d = smem + ((t & 1) << 15) + (h << 14) + (tid << 4);
        gload_lds16(Abase + ((size_t)(h * 128)      ) * lda + t * 64, d);
        gload_lds16(Abase + ((size_t)(h * 128) + 64 ) * lda + t * 64, d + 8192);
    };
    auto stB = [&](int t, int h) {
        char* d = smem + 65536 + (t & 1) * (NBH * 16384) + (h << 14) + (tid << 4);
        gload_lds16(Bbase + ((size_t)(h * 128)      ) * ldb + t * 64, d);
        gload_lds16(Bbase + ((size_t)(h * 128) + 64 ) * ldb + t * 64, d + 8192);
    };
    auto rdA = [&](int t, int m, int kk) -> bf16x8 {
        int r = m * 16 + frow;
        return *(const bf16x8*)(smem + ((t & 1) << 15) + (wr << 14)
                + r * 128 + ((((kk << 2) + fg) ^ (frow & 7)) << 4));
    };
    auto rdB = [&](int t, int n, int kk) -> bf16x8 {
        int br = wc * (BN / 4) + n * 16 + frow;
        return *(const bf16x8*)(smem + 65536 + (t & 1) * (NBH * 16384) + ((br >> 7) << 14)
                + (br & 127) * 128 + ((((kk << 2) + fg) ^ (frow & 7)) << 4));
    };

    f32x4 acc[8][NR] = {};
    bf16x8 aLo[4][2], aHi[4][2], bLo[NHF][2], bHi[NHF][2];

#define MMQ(MO, NO, AARR, BARR) \
    _Pragma("unroll") for (int m_ = 0; m_ < 4; ++m_) \
    _Pragma("unroll") for (int n_ = 0; n_ < NHF; ++n_) \
    _Pragma("unroll") for (int k_ = 0; k_ < 2; ++k_) \
        acc[m_ + MO][n_ + NO] = __builtin_amdgcn_mfma_f32_16x16x32_bf16( \
            AARR[m_][k_], BARR[n_][k_], acc[m_ + MO][n_ + NO], 0, 0, 0);

    stA(0, 0); stA(0, 1);
    stB(0, 0); if constexpr (NBH == 2) stB(0, 1);
    stA(1, 0); stA(1, 1);
    if constexpr (NBH == 2) { stB(1, 0); WAITV(6); } else { WAITV(4); }
    BAR();

    for (int t = 0; t < NT; ++t) {
        if (t + 1 < NT) stB(t + 1, NBH - 1);
        #pragma unroll
        for (int m_ = 0; m_ < 4; ++m_) { aLo[m_][0] = rdA(t, m_, 0); aLo[m_][1] = rdA(t, m_, 1); }
        #pragma unroll
        for (int n_ = 0; n_ < NHF; ++n_) { bLo[n_][0] = rdB(t, n_, 0); bLo[n_][1] = rdB(t, n_, 1); }
        #pragma unroll
        for (int n_ = 0; n_ < NHF; ++n_) { bHi[n_][0] = rdB(t, NHF + n_, 0); bHi[n_][1] = rdB(t, NHF + n_, 1); }
        #pragma unroll
        for (int m_ = 0; m_ < 4; ++m_) { aHi[m_][0] = rdA(t, 4 + m_, 0); aHi[m_][1] = rdA(t, 4 + m_, 1); }
        __builtin_amdgcn_s_setprio(1);
        MMQ(0, 0, aLo, bLo);
        MMQ(0, NHF, aLo, bHi);
        __builtin_amdgcn_s_setprio(0);
        WAITL0();
        BAR();
        if (t + 2 < NT) {
            stA(t + 2, 0); stA(t + 2, 1);
            if constexpr (NBH == 2) stB(t + 2, 0);
        }
        __builtin_amdgcn_s_setprio(1);
        MMQ(4, NHF, aHi, bHi);
        MMQ(4, 0, aHi, bLo);
        __builtin_amdgcn_s_setprio(0);
        if (t + 2 < NT) {
            if constexpr (NBH == 2) WAITV(6); else WAITV(4);
        } else if (t + 1 < NT) {
            WAITV(0);
        }
        BAR();
    }
#undef MMQ

    const size_t crow0 = (size_t)bm * 256 + wr * 128 + (fg << 2);
    const size_t ccol0 = (size_t)bn * BN + wc * (BN / 4) + frow;
    if constexpr (EPI == 1) {
        const int panel = (int)(ccol0 >> 10);            // 0=Q, 1=K, 2=V
        const size_t pcol0 = ccol0 & 1023;
        if (panel < 2) {
            int8_t* dst = (panel == 0) ? q8 : k8;
            #pragma unroll
            for (int m = 0; m < 8; ++m)
                #pragma unroll
                for (int n = 0; n < NR; ++n)
                    #pragma unroll
                    for (int i = 0; i < 4; ++i)
                        dst[(crow0 + m * 16 + i) * 1024 + pcol0 + n * 16] =
                            (int8_t)qi8(acc[m][n][i] * QSC);
        } else {
            // V panel: in-LDS transpose (two 128-col halves), write VT[1024][8192]
            bf16* tl = (bf16*)smem;                      // [128][264] bf16
            const int vcb  = (bn & 3) * 256;             // block's V col base
            const int lrow = wr * 128 + (fg << 2);       // local row base (+ m*16)
            #pragma unroll
            for (int h = 0; h < 2; ++h) {
                BAR();
                if ((wc >> 1) == h) {                    // wave-uniform branch
                    const int lc = (wc & 1) * 64 + frow; // col within half
                    #pragma unroll
                    for (int m = 0; m < 8; ++m)
                        #pragma unroll
                        for (int n = 0; n < 4; ++n) {
                            bf16x4 v;
                            #pragma unroll
                            for (int i = 0; i < 4; ++i) v[i] = (bf16)acc[m][n][i];
                            *(bf16x4*)&tl[(lc + n * 16) * 264 + lrow + m * 16] = v;
                        }
                }
                BAR();
                #pragma unroll
                for (int j = 0; j < 8; ++j) {
                    int cid = j * 512 + tid;             // 0..4095
                    int c   = cid >> 5;                  // 0..127
                    int rc  = (cid & 31) << 3;           // 0..248
                    bf16x8 v = *(const bf16x8*)&tl[c * 264 + rc];
                    *(bf16x8*)&vt[(size_t)(vcb + h * 128 + c) * 8192 + bm * 256 + rc] = v;
                }
            }
        }
    } else {
        #pragma unroll
        for (int m = 0; m < 8; ++m)
            #pragma unroll
            for (int n = 0; n < NR; ++n)
                #pragma unroll
                for (int i = 0; i < 4; ++i)
                    Cp[(crow0 + m * 16 + i) * ldc + ccol0 + n * 16] = (CT)(acc[m][n][i]);
    }
}

// ====== int8 QK^T -> bf16 E = exp(acc/41472) + fused LDS row-sums (r16 verified) ======
__global__ __launch_bounds__(512, 2) void gemmEi8(const int8_t* __restrict__ A,
                                                  const int8_t* __restrict__ B,
                                                  bf16* __restrict__ E,
                                                  float* __restrict__ sums,
                                                  int K, int ld, int ldc, int nbn) {
    __shared__ char smem[131072];   // A dbuf 2x32KB @0 | B dbuf 2x32KB @65536

    const int tid  = threadIdx.x;
    const int lane = tid & 63;
    const int wave = tid >> 6;
    const int wr   = wave >> 2;           // 0..1
    const int wc   = wave & 3;            // 0..3
    const int frow = lane & 15;
    const int fg   = lane >> 4;           // 0..3

    const int cpx = gridDim.x >> 3;
    const int swz = ((int)blockIdx.x & 7) * cpx + ((int)blockIdx.x >> 3);
    const int bm = swz / nbn, bn = swz % nbn;
    const int NT = K >> 7;                // 8

    const int r0 = tid >> 3;
    const int c0 = ((tid & 7) ^ (r0 & 7)) << 4;     // inv-swizzled byte col
    const int8_t* Abase = A + (size_t)(bm * 256 + r0) * ld + c0;
    const int8_t* Bbase = B + (size_t)(bn * 256 + r0) * ld + c0;

    auto stA = [&](int t, int h) {
        char* d = smem + ((t & 1) << 15) + (h << 14) + (tid << 4);
        gload_lds16(Abase + ((size_t)(h * 128)     ) * ld + t * 128, d);
        gload_lds16(Abase + ((size_t)(h * 128) + 64) * ld + t * 128, d + 8192);
    };
    auto stB = [&](int t, int h) {
        char* d = smem + 65536 + ((t & 1) << 15) + (h << 14) + (tid << 4);
        gload_lds16(Bbase + ((size_t)(h * 128)     ) * ld + t * 128, d);
        gload_lds16(Bbase + ((size_t)(h * 128) + 64) * ld + t * 128, d + 8192);
    };
    auto rdA = [&](int t, int m, int kk) -> i32x4 {   // m in [0,8)
        int r = m * 16 + frow;
        return *(const i32x4*)(smem + ((t & 1) << 15) + (wr << 14)
                + r * 128 + ((((kk << 2) + fg) ^ (frow & 7)) << 4));
    };
    auto rdB = [&](int t, int n, int kk) -> i32x4 {   // n in [0,4)
        int br = wc * 64 + n * 16 + frow;
        return *(const i32x4*)(smem + 65536 + ((t & 1) << 15) + ((br >> 7) << 14)
                + (br & 127) * 128 + ((((kk << 2) + fg) ^ (frow & 7)) << 4));
    };

    i32x4 acc[8][4] = {};
    i32x4 aLo[4][2], aHi[4][2], bLo[2][2], bHi[2][2];

#define MMQ(MO, NO, AARR, BARR) \
    _Pragma("unroll") for (int m_ = 0; m_ < 4; ++m_) \
    _Pragma("unroll") for (int n_ = 0; n_ < 2; ++n_) \
    _Pragma("unroll") for (int k_ = 0; k_ < 2; ++k_) \
        acc[m_ + MO][n_ + NO] = __builtin_amdgcn_mfma_i32_16x16x64_i8( \
            AARR[m_][k_], BARR[n_][k_], acc[m_ + MO][n_ + NO], 0, 0, 0);

    stA(0, 0); stA(0, 1);
    stB(0, 0); stB(0, 1);
    stA(1, 0); stA(1, 1);
    stB(1, 0); WAITV(6);
    BAR();

    for (int t = 0; t < NT; ++t) {
        if (t + 1 < NT) stB(t + 1, 1);
        #pragma unroll
        for (int m_ = 0; m_ < 4; ++m_) { aLo[m_][0] = rdA(t, m_, 0); aLo[m_][1] = rdA(t, m_, 1); }
        #pragma unroll
        for (int n_ = 0; n_ < 2; ++n_) { bLo[n_][0] = rdB(t, n_, 0); bLo[n_][1] = rdB(t, n_, 1); }
        #pragma unroll
        for (int n_ = 0; n_ < 2; ++n_) { bHi[n_][0] = rdB(t, 2 + n_, 0); bHi[n_][1] = rdB(t, 2 + n_, 1); }
        #pragma unroll
        for (int m_ = 0; m_ < 4; ++m_) { aHi[m_][0] = rdA(t, 4 + m_, 0); aHi[m_][1] = rdA(t, 4 + m_, 1); }
        __builtin_amdgcn_s_setprio(1);
        MMQ(0, 0, aLo, bLo);
        MMQ(0, 2, aLo, bHi);
        __builtin_amdgcn_s_setprio(0);
        WAITL0();
        BAR();
        if (t + 2 < NT) { stA(t + 2, 0); stA(t + 2, 1); stB(t + 2, 0); }
        __builtin_amdgcn_s_setprio(1);
        MMQ(4, 2, aHi, bHi);
        MMQ(4, 0, aHi, bLo);
        __builtin_amdgcn_s_setprio(0);
        if (t + 2 < NT)      { WAITV(6); }
        else if (t + 1 < NT) { WAITV(0); }
        BAR();
    }
#undef MMQ

    // epilogue: E = exp(acc * QDQ) + LDS row-partial reduction (r16 verified)
    const size_t crow0 = (size_t)bm * 256 + wr * 128 + (fg << 2);
    const size_t ccol0 = (size_t)bn * 256 + wc * 64 + frow;
    float* part = (float*)smem;                 // [256][66] floats
    const int rl0 = wr * 128 + (fg << 2);
    const int ent = wc * 16 + frow;
    #pragma unroll
    for (int m = 0; m < 8; ++m)
        #pragma unroll
        for (int i = 0; i < 4; ++i) {
            float s = 0.f;
            #pragma unroll
            for (int n = 0; n < 4; ++n) {
                float e = __expf((float)acc[m][n][i] * QDQ);
                bf16 b = (bf16)e;
                E[(crow0 + m * 16 + i) * ldc + ccol0 + n * 16] = b;
                s += (float)b;
            }
            part[(rl0 + m * 16 + i) * 66 + ent] = s;
        }
    __syncthreads();
    if (tid < 256) {
        float s = 0.f;
        const float* pr = part + tid * 66;
        #pragma unroll 8
        for (int e = 0; e < 64; ++e) s += pr[e];
        atomicAdd(&sums[(size_t)bm * 256 + tid], s);
    }
}

// ------- out[i] = (out[i] + part[i]) / sums[row], float4 -------
__global__ __launch_bounds__(256) void add_scale(float* __restrict__ out,
                                                 const float* __restrict__ part,
                                                 const float* __restrict__ sums, int n4) {
    int i = blockIdx.x * 256 + threadIdx.x;
    if (i >= n4) return;
    const float sc = 1.0f / sums[i >> 8];
    float4 a = ((const float4*)out)[i];
    float4 b = ((const float4*)part)[i];
    a.x = (a.x + b.x) * sc; a.y = (a.y + b.y) * sc;
    a.z = (a.z + b.z) * sc; a.w = (a.w + b.w) * sc;
    ((float4*)out)[i] = a;
}

extern "C" void kernel_launch(void* const* d_in, const int* in_sizes, int n_in,
                              void* d_out, int out_size, void* d_ws, size_t ws_size,
                              hipStream_t stream) {
    const float* h  = (const float*)d_in[0];
    const float* wq = (const float*)d_in[1];
    const float* wk = (const float*)d_in[2];
    const float* wv = (const float*)d_in[3];
    float* out = (float*)d_out;

    char* ws = (char*)d_ws;
    bf16*   h_bf = (bf16*)(ws);                         // 16 MB [8192 x 1024]
    bf16*   wcat = (bf16*)(ws + (16ull << 20));         //  6 MB [3072 x 1024]
    int8_t* Qi8  = (int8_t*)(ws + (22ull << 20));       //  8 MB [8192 x 1024]
    int8_t* Ki8  = (int8_t*)(ws + (30ull << 20));       //  8 MB
    bf16*   VT   = (bf16*)(ws + (38ull << 20));         // 16 MB [1024 x 8192]
    bf16*   E    = (bf16*)(ws + (54ull << 20));         // 128 MB [8192 x 8192]
    float*  sums = (float*)(ws + (182ull << 20));       // 32 KB
    float*  Pv   = (float*)(ws);                        // 32 MB (h_bf..Ki8 dead by PV)

    // 1) fused prep: inputs -> bf16 + zero sums (one dispatch)
    prep<<<11272, 256, 0, stream>>>(h, wq, wk, wv, h_bf, wcat, sums);

    // 2) fused QKV projection: Q,K -> int8, V -> VT direct (in-LDS transpose), grid 384
    gemmW<bf16, 256, 1, 1><<<384, 512, 0, stream>>>(h_bf, wcat, nullptr, nullptr,
                                                    Qi8, Ki8, VT,
                                                    1024, 1024, 1024, 1024, 12);

    // 3) E = exp((Qi8 . Ki8)/41472) + fused LDS row-sums, grid 1024
    gemmEi8<<<1024, 512, 0, stream>>>(Qi8, Ki8, E, sums, 1024, 1024, 8192, 32);

    // 4) P = E @ VT^T, plain split-K=2 stores, grid 256
    gemmW<float, 256, 2, 0><<<256, 512, 0, stream>>>(E, VT, out, Pv,
                                                     nullptr, nullptr, nullptr,
                                                     4096, 8192, 8192, 1024, 4);

    // 5) out = (P0 + P1) / sums[row]
    add_scale<<<8192, 256, 0, stream>>>(out, Pv, sums, (8192 * 1024) / 4);
}

// Round 20
// 289.718 us; speedup vs baseline: 1.1486x; 1.0206x over previous
//
#include <hip/hip_runtime.h>
#include <hip/hip_bf16.h>
#include <stdint.h>
#include <math.h>

typedef __bf16 bf16;
typedef __bf16 bf16x8 __attribute__((ext_vector_type(8)));
typedef __bf16 bf16x4 __attribute__((ext_vector_type(4)));
typedef float  f32x4  __attribute__((ext_vector_type(4)));
typedef int    i32x4  __attribute__((ext_vector_type(4)));

#define AS_GLOBAL __attribute__((address_space(1)))
#define AS_LDS    __attribute__((address_space(3)))

__device__ __forceinline__ void gload_lds16(const void* g, void* l) {
    __builtin_amdgcn_global_load_lds((const AS_GLOBAL uint32_t*)g,
                                     (AS_LDS uint32_t*)l, 16, 0, 0);
}
__device__ __forceinline__ void cfence() { asm volatile("" ::: "memory"); }
#define BAR()    do { cfence(); __builtin_amdgcn_s_barrier(); cfence(); } while (0)
#define WAITV(n) asm volatile("s_waitcnt vmcnt(" #n ")" ::: "memory")
#define WAITL0() asm volatile("s_waitcnt lgkmcnt(0)" ::: "memory")

#define QSC 36.0f                            // q/k int8 scale
#define QDQ (1.0f / (QSC * QSC * 32.0f))     // logit dequant incl 1/sqrt(1024)

__device__ __forceinline__ int qi8(float f) {
    int q = (int)rintf(f);
    return q > 127 ? 127 : (q < -127 ? -127 : q);
}

// ---- fused prep: h->bf16 (8192 blk), wq/wk/wv->wcat (3x1024 blk), zero sums (8 blk) ----
__global__ __launch_bounds__(256) void prep(const float* __restrict__ h,
                                            const float* __restrict__ wq,
                                            const float* __restrict__ wk,
                                            const float* __restrict__ wv,
                                            bf16* __restrict__ h_bf,
                                            bf16* __restrict__ wcat,
                                            float* __restrict__ sums) {
    const int b = blockIdx.x;
    if (b < 11264) {
        const float* src;
        bf16* dst;
        int i;
        if (b < 8192)      { src = h;  dst = h_bf;                i = b * 256 + threadIdx.x; }
        else if (b < 9216) { src = wq; dst = wcat;                i = (b - 8192) * 256 + threadIdx.x; }
        else if (b < 10240){ src = wk; dst = wcat + 1024 * 1024;  i = (b - 9216) * 256 + threadIdx.x; }
        else               { src = wv; dst = wcat + 2048 * 1024;  i = (b - 10240) * 256 + threadIdx.x; }
        float4 v = ((const float4*)src)[i];
        bf16x4 o;
        o[0] = (bf16)v.x; o[1] = (bf16)v.y; o[2] = (bf16)v.z; o[3] = (bf16)v.w;
        *(bf16x4*)(dst + (size_t)i * 4) = o;
    } else {
        int i = (b - 11264) * 256 + threadIdx.x;
        if (i < 2048) ((float4*)sums)[i] = make_float4(0.f, 0.f, 0.f, 0.f);
    }
}

// ====== 2-window/K-tile bf16 GEMM (r7..r19 verified): C = A * B^T ======
// EPI=0: plain CT store (+split-K); CT=bf16 for PV partials (halved traffic).
// EPI=1: QKV epilogue — panel 0 -> Qi8 (x36), 1 -> Ki8, 2 -> VT direct
//        (in-LDS transpose).  r17 lesson: NO atomic epilogue (+37 µs L2-RMW).
template<typename CT, int BN, int SPLIT, int EPI>
__global__ __launch_bounds__(512, 2) void gemmW(const bf16* __restrict__ A,
                                                const bf16* __restrict__ B,
                                                CT* __restrict__ C,
                                                CT* __restrict__ C2,
                                                int8_t* __restrict__ q8,
                                                int8_t* __restrict__ k8,
                                                bf16* __restrict__ vt,
                                                int K, int lda, int ldb, int ldc,
                                                int nbn) {
    constexpr int NBH = BN / 128;
    constexpr int NR  = BN / 64;
    constexpr int NHF = NR / 2;
    __shared__ char smem[65536 + NBH * 32768];

    const int tid  = threadIdx.x;
    const int lane = tid & 63;
    const int wave = tid >> 6;
    const int wr   = wave >> 2;
    const int wc   = wave & 3;
    const int frow = lane & 15;
    const int fg   = lane >> 4;

    const int cpx = gridDim.x >> 3;
    const int swz = ((int)blockIdx.x & 7) * cpx + ((int)blockIdx.x >> 3);
    int id = swz, s = 0;
    if (SPLIT == 2) { s = id & 1; id >>= 1; }
    const int bm = id / nbn, bn = id % nbn;
    const int NT = K >> 6;
    const size_t koff = (size_t)s * K;
    CT* Cp = (SPLIT == 2 && s == 1) ? C2 : C;

    const int r0 = tid >> 3;
    const int c0 = ((tid & 7) ^ (r0 & 7)) << 3;
    const bf16* Abase = A + (size_t)(bm * 256 + r0) * lda + c0 + koff;
    const bf16* Bbase = B + (size_t)(bn * BN + r0) * ldb + c0 + koff;

    auto stA = [&](int t, int h) {
        char* d = smem + ((t & 1) << 15) + (h << 14) + (tid << 4);
        gload_lds16(Abase + ((size_t)(h * 128)      ) * lda + t * 64, d);
        gload_lds16(Abase + ((size_t)(h * 128) + 64 ) * lda + t * 64, d + 8192);
    };
    auto stB = [&](int t, int h) {
        char* d = smem + 65536 + (t & 1) * (NBH * 16384) + (h << 14) + (tid << 4);
        gload_lds16(Bbase + ((size_t)(h * 128)      ) * ldb + t * 64, d);
        gload_lds16(Bbase + ((size_t)(h * 128) + 64 ) * ldb + t * 64, d + 8192);
    };
    auto rdA = [&](int t, int m, int kk) -> bf16x8 {
        int r = m * 16 + frow;
        return *(const bf16x8*)(smem + ((t & 1) << 15) + (wr << 14)
                + r * 128 + ((((kk << 2) + fg) ^ (frow & 7)) << 4));
    };
    auto rdB = [&](int t, int n, int kk) -> bf16x8 {
        int br = wc * (BN / 4) + n * 16 + frow;
        return *(const bf16x8*)(smem + 65536 + (t & 1) * (NBH * 16384) + ((br >> 7) << 14)
                + (br & 127) * 128 + ((((kk << 2) + fg) ^ (frow & 7)) << 4));
    };

    f32x4 acc[8][NR] = {};
    bf16x8 aLo[4][2], aHi[4][2], bLo[NHF][2], bHi[NHF][2];

#define MMQ(MO, NO, AARR, BARR) \
    _Pragma("unroll") for (int m_ = 0; m_ < 4; ++m_) \
    _Pragma("unroll") for (int n_ = 0; n_ < NHF; ++n_) \
    _Pragma("unroll") for (int k_ = 0; k_ < 2; ++k_) \
        acc[m_ + MO][n_ + NO] = __builtin_amdgcn_mfma_f32_16x16x32_bf16( \
            AARR[m_][k_], BARR[n_][k_], acc[m_ + MO][n_ + NO], 0, 0, 0);

    stA(0, 0); stA(0, 1);
    stB(0, 0); if constexpr (NBH == 2) stB(0, 1);
    stA(1, 0); stA(1, 1);
    if constexpr (NBH == 2) { stB(1, 0); WAITV(6); } else { WAITV(4); }
    BAR();

    for (int t = 0; t < NT; ++t) {
        if (t + 1 < NT) stB(t + 1, NBH - 1);
        #pragma unroll
        for (int m_ = 0; m_ < 4; ++m_) { aLo[m_][0] = rdA(t, m_, 0); aLo[m_][1] = rdA(t, m_, 1); }
        #pragma unroll
        for (int n_ = 0; n_ < NHF; ++n_) { bLo[n_][0] = rdB(t, n_, 0); bLo[n_][1] = rdB(t, n_, 1); }
        #pragma unroll
        for (int n_ = 0; n_ < NHF; ++n_) { bHi[n_][0] = rdB(t, NHF + n_, 0); bHi[n_][1] = rdB(t, NHF + n_, 1); }
        #pragma unroll
        for (int m_ = 0; m_ < 4; ++m_) { aHi[m_][0] = rdA(t, 4 + m_, 0); aHi[m_][1] = rdA(t, 4 + m_, 1); }
        __builtin_amdgcn_s_setprio(1);
        MMQ(0, 0, aLo, bLo);
        MMQ(0, NHF, aLo, bHi);
        __builtin_amdgcn_s_setprio(0);
        WAITL0();
        BAR();
        if (t + 2 < NT) {
            stA(t + 2, 0); stA(t + 2, 1);
            if constexpr (NBH == 2) stB(t + 2, 0);
        }
        __builtin_amdgcn_s_setprio(1);
        MMQ(4, NHF, aHi, bHi);
        MMQ(4, 0, aHi, bLo);
        __builtin_amdgcn_s_setprio(0);
        if (t + 2 < NT) {
            if constexpr (NBH == 2) WAITV(6); else WAITV(4);
        } else if (t + 1 < NT) {
            WAITV(0);
        }
        BAR();
    }
#undef MMQ

    const size_t crow0 = (size_t)bm * 256 + wr * 128 + (fg << 2);
    const size_t ccol0 = (size_t)bn * BN + wc * (BN / 4) + frow;
    if constexpr (EPI == 1) {
        const int panel = (int)(ccol0 >> 10);            // 0=Q, 1=K, 2=V
        const size_t pcol0 = ccol0 & 1023;
        if (panel < 2) {
            int8_t* dst = (panel == 0) ? q8 : k8;
            #pragma unroll
            for (int m = 0; m < 8; ++m)
                #pragma unroll
                for (int n = 0; n < NR; ++n)
                    #pragma unroll
                    for (int i = 0; i < 4; ++i)
                        dst[(crow0 + m * 16 + i) * 1024 + pcol0 + n * 16] =
                            (int8_t)qi8(acc[m][n][i] * QSC);
        } else {
            // V panel: in-LDS transpose (two 128-col halves), write VT[1024][8192]
            bf16* tl = (bf16*)smem;                      // [128][264] bf16
            const int vcb  = (bn & 3) * 256;             // block's V col base
            const int lrow = wr * 128 + (fg << 2);       // local row base (+ m*16)
            #pragma unroll
            for (int h = 0; h < 2; ++h) {
                BAR();
                if ((wc >> 1) == h) {                    // wave-uniform branch
                    const int lc = (wc & 1) * 64 + frow; // col within half
                    #pragma unroll
                    for (int m = 0; m < 8; ++m)
                        #pragma unroll
                        for (int n = 0; n < 4; ++n) {
                            bf16x4 v;
                            #pragma unroll
                            for (int i = 0; i < 4; ++i) v[i] = (bf16)acc[m][n][i];
                            *(bf16x4*)&tl[(lc + n * 16) * 264 + lrow + m * 16] = v;
                        }
                }
                BAR();
                #pragma unroll
                for (int j = 0; j < 8; ++j) {
                    int cid = j * 512 + tid;             // 0..4095
                    int c   = cid >> 5;                  // 0..127
                    int rc  = (cid & 31) << 3;           // 0..248
                    bf16x8 v = *(const bf16x8*)&tl[c * 264 + rc];
                    *(bf16x8*)&vt[(size_t)(vcb + h * 128 + c) * 8192 + bm * 256 + rc] = v;
                }
            }
        }
    } else {
        #pragma unroll
        for (int m = 0; m < 8; ++m)
            #pragma unroll
            for (int n = 0; n < NR; ++n)
                #pragma unroll
                for (int i = 0; i < 4; ++i)
                    Cp[(crow0 + m * 16 + i) * ldc + ccol0 + n * 16] = (CT)(acc[m][n][i]);
    }
}

// ====== int8 QK^T -> bf16 E = exp(acc/41472) + fused LDS row-sums (r16 verified) ======
__global__ __launch_bounds__(512, 2) void gemmEi8(const int8_t* __restrict__ A,
                                                  const int8_t* __restrict__ B,
                                                  bf16* __restrict__ E,
                                                  float* __restrict__ sums,
                                                  int K, int ld, int ldc, int nbn) {
    __shared__ char smem[131072];   // A dbuf 2x32KB @0 | B dbuf 2x32KB @65536

    const int tid  = threadIdx.x;
    const int lane = tid & 63;
    const int wave = tid >> 6;
    const int wr   = wave >> 2;           // 0..1
    const int wc   = wave & 3;            // 0..3
    const int frow = lane & 15;
    const int fg   = lane >> 4;           // 0..3

    const int cpx = gridDim.x >> 3;
    const int swz = ((int)blockIdx.x & 7) * cpx + ((int)blockIdx.x >> 3);
    const int bm = swz / nbn, bn = swz % nbn;
    const int NT = K >> 7;                // 8

    const int r0 = tid >> 3;
    const int c0 = ((tid & 7) ^ (r0 & 7)) << 4;     // inv-swizzled byte col
    const int8_t* Abase = A + (size_t)(bm * 256 + r0) * ld + c0;
    const int8_t* Bbase = B + (size_t)(bn * 256 + r0) * ld + c0;

    auto stA = [&](int t, int h) {
        char* d = smem + ((t & 1) << 15) + (h << 14) + (tid << 4);
        gload_lds16(Abase + ((size_t)(h * 128)     ) * ld + t * 128, d);
        gload_lds16(Abase + ((size_t)(h * 128) + 64) * ld + t * 128, d + 8192);
    };
    auto stB = [&](int t, int h) {
        char* d = smem + 65536 + ((t & 1) << 15) + (h << 14) + (tid << 4);
        gload_lds16(Bbase + ((size_t)(h * 128)     ) * ld + t * 128, d);
        gload_lds16(Bbase + ((size_t)(h * 128) + 64) * ld + t * 128, d + 8192);
    };
    auto rdA = [&](int t, int m, int kk) -> i32x4 {   // m in [0,8)
        int r = m * 16 + frow;
        return *(const i32x4*)(smem + ((t & 1) << 15) + (wr << 14)
                + r * 128 + ((((kk << 2) + fg) ^ (frow & 7)) << 4));
    };
    auto rdB = [&](int t, int n, int kk) -> i32x4 {   // n in [0,4)
        int br = wc * 64 + n * 16 + frow;
        return *(const i32x4*)(smem + 65536 + ((t & 1) << 15) + ((br >> 7) << 14)
                + (br & 127) * 128 + ((((kk << 2) + fg) ^ (frow & 7)) << 4));
    };

    i32x4 acc[8][4] = {};
    i32x4 aLo[4][2], aHi[4][2], bLo[2][2], bHi[2][2];

#define MMQ(MO, NO, AARR, BARR) \
    _Pragma("unroll") for (int m_ = 0; m_ < 4; ++m_) \
    _Pragma("unroll") for (int n_ = 0; n_ < 2; ++n_) \
    _Pragma("unroll") for (int k_ = 0; k_ < 2; ++k_) \
        acc[m_ + MO][n_ + NO] = __builtin_amdgcn_mfma_i32_16x16x64_i8( \
            AARR[m_][k_], BARR[n_][k_], acc[m_ + MO][n_ + NO], 0, 0, 0);

    stA(0, 0); stA(0, 1);
    stB(0, 0); stB(0, 1);
    stA(1, 0); stA(1, 1);
    stB(1, 0); WAITV(6);
    BAR();

    for (int t = 0; t < NT; ++t) {
        if (t + 1 < NT) stB(t + 1, 1);
        #pragma unroll
        for (int m_ = 0; m_ < 4; ++m_) { aLo[m_][0] = rdA(t, m_, 0); aLo[m_][1] = rdA(t, m_, 1); }
        #pragma unroll
        for (int n_ = 0; n_ < 2; ++n_) { bLo[n_][0] = rdB(t, n_, 0); bLo[n_][1] = rdB(t, n_, 1); }
        #pragma unroll
        for (int n_ = 0; n_ < 2; ++n_) { bHi[n_][0] = rdB(t, 2 + n_, 0); bHi[n_][1] = rdB(t, 2 + n_, 1); }
        #pragma unroll
        for (int m_ = 0; m_ < 4; ++m_) { aHi[m_][0] = rdA(t, 4 + m_, 0); aHi[m_][1] = rdA(t, 4 + m_, 1); }
        __builtin_amdgcn_s_setprio(1);
        MMQ(0, 0, aLo, bLo);
        MMQ(0, 2, aLo, bHi);
        __builtin_amdgcn_s_setprio(0);
        WAITL0();
        BAR();
        if (t + 2 < NT) { stA(t + 2, 0); stA(t + 2, 1); stB(t + 2, 0); }
        __builtin_amdgcn_s_setprio(1);
        MMQ(4, 2, aHi, bHi);
        MMQ(4, 0, aHi, bLo);
        __builtin_amdgcn_s_setprio(0);
        if (t + 2 < NT)      { WAITV(6); }
        else if (t + 1 < NT) { WAITV(0); }
        BAR();
    }
#undef MMQ

    // epilogue: E = exp(acc * QDQ) + LDS row-partial reduction (r16 verified)
    const size_t crow0 = (size_t)bm * 256 + wr * 128 + (fg << 2);
    const size_t ccol0 = (size_t)bn * 256 + wc * 64 + frow;
    float* part = (float*)smem;                 // [256][66] floats
    const int rl0 = wr * 128 + (fg << 2);
    const int ent = wc * 16 + frow;
    #pragma unroll
    for (int m = 0; m < 8; ++m)
        #pragma unroll
        for (int i = 0; i < 4; ++i) {
            float s = 0.f;
            #pragma unroll
            for (int n = 0; n < 4; ++n) {
                float e = __expf((float)acc[m][n][i] * QDQ);
                bf16 b = (bf16)e;
                E[(crow0 + m * 16 + i) * ldc + ccol0 + n * 16] = b;
                s += (float)b;
            }
            part[(rl0 + m * 16 + i) * 66 + ent] = s;
        }
    __syncthreads();
    if (tid < 256) {
        float s = 0.f;
        const float* pr = part + tid * 66;
        #pragma unroll 8
        for (int e = 0; e < 64; ++e) s += pr[e];
        atomicAdd(&sums[(size_t)bm * 256 + tid], s);
    }
}

// ------- out[i] = (P0[i] + P1[i]) / sums[row]  (bf16 partials, f32 out) -------
__global__ __launch_bounds__(256) void add_scale_bf(float* __restrict__ out,
                                                    const bf16* __restrict__ P0,
                                                    const bf16* __restrict__ P1,
                                                    const float* __restrict__ sums, int n4) {
    int i = blockIdx.x * 256 + threadIdx.x;
    if (i >= n4) return;
    const float sc = 1.0f / sums[i >> 8];          // 256 float4 per 1024-wide row
    bf16x4 a = *(const bf16x4*)(P0 + (size_t)i * 4);
    bf16x4 b = *(const bf16x4*)(P1 + (size_t)i * 4);
    float4 o;
    o.x = ((float)a[0] + (float)b[0]) * sc;
    o.y = ((float)a[1] + (float)b[1]) * sc;
    o.z = ((float)a[2] + (float)b[2]) * sc;
    o.w = ((float)a[3] + (float)b[3]) * sc;
    ((float4*)out)[i] = o;
}

extern "C" void kernel_launch(void* const* d_in, const int* in_sizes, int n_in,
                              void* d_out, int out_size, void* d_ws, size_t ws_size,
                              hipStream_t stream) {
    const float* h  = (const float*)d_in[0];
    const float* wq = (const float*)d_in[1];
    const float* wk = (const float*)d_in[2];
    const float* wv = (const float*)d_in[3];
    float* out = (float*)d_out;

    char* ws = (char*)d_ws;
    bf16*   h_bf = (bf16*)(ws);                         // 16 MB [8192 x 1024]
    bf16*   wcat = (bf16*)(ws + (16ull << 20));         //  6 MB [3072 x 1024]
    int8_t* Qi8  = (int8_t*)(ws + (22ull << 20));       //  8 MB [8192 x 1024]
    int8_t* Ki8  = (int8_t*)(ws + (30ull << 20));       //  8 MB
    bf16*   VT   = (bf16*)(ws + (38ull << 20));         // 16 MB [1024 x 8192]
    bf16*   E    = (bf16*)(ws + (54ull << 20));         // 128 MB [8192 x 8192]
    float*  sums = (float*)(ws + (182ull << 20));       // 32 KB
    bf16*   P0   = (bf16*)(ws);                         // 16 MB (h_bf dead by PV)
    bf16*   P1   = (bf16*)(ws + (16ull << 20));         // 16 MB (wcat/Qi8 dead by PV)

    // 1) fused prep: inputs -> bf16 + zero sums (one dispatch)
    prep<<<11272, 256, 0, stream>>>(h, wq, wk, wv, h_bf, wcat, sums);

    // 2) fused QKV projection: Q,K -> int8, V -> VT direct (in-LDS transpose), grid 384
    gemmW<bf16, 256, 1, 1><<<384, 512, 0, stream>>>(h_bf, wcat, nullptr, nullptr,
                                                    Qi8, Ki8, VT,
                                                    1024, 1024, 1024, 1024, 12);

    // 3) E = exp((Qi8 . Ki8)/41472) + fused LDS row-sums, grid 1024
    gemmEi8<<<1024, 512, 0, stream>>>(Qi8, Ki8, E, sums, 1024, 1024, 8192, 32);

    // 4) P = E @ VT^T, split-K=2, bf16 partial stores (halved write traffic), grid 256
    gemmW<bf16, 256, 2, 0><<<256, 512, 0, stream>>>(E, VT, P0, P1,
                                                    nullptr, nullptr, nullptr,
                                                    4096, 8192, 8192, 1024, 4);

    // 5) out = (P0 + P1) / sums[row]
    add_scale_bf<<<8192, 256, 0, stream>>>(out, P0, P1, sums, (8192 * 1024) / 4);
}